// Round 10
// baseline (388.198 us; speedup 1.0000x reference)
//
#include <hip/hip_runtime.h>
#include <hip/hip_cooperative_groups.h>

namespace cg = cooperative_groups;

typedef unsigned short u16;
typedef short bf16x8 __attribute__((ext_vector_type(8)));   // 8 bf16 in 4 VGPRs
typedef float f32x4 __attribute__((ext_vector_type(4)));

__device__ __constant__ const int DRS[8] = {-1,-1,-1, 0, 0, 1, 1, 1};
__device__ __constant__ const int DCS[8] = {-1, 0, 1,-1, 1,-1, 0, 1};

__device__ inline float bf2f(u16 u) { return __uint_as_float(((unsigned)u) << 16); }
__device__ inline u16 f2bf(float f) {            // round-to-nearest-even
  unsigned u = __float_as_uint(f);
  return (u16)((u + 0x7fffu + ((u >> 16) & 1u)) >> 16);
}
__device__ inline float eluf(float v) { return v > 0.f ? v : (__expf(v) - 1.f); }
__device__ inline unsigned pk2(float a, float b) {
  return (unsigned)f2bf(a) | ((unsigned)f2bf(b) << 16);
}

// collapse degree-1 B-spline weights for grid direction d (0..7, center skipped)
__device__ inline float weff_val(const float* __restrict__ W, int d, int off, int stride) {
  int dd = d >= 4 ? d + 1 : d;
  int dr = dd / 3 - 1, dc = dd - (dd / 3) * 3 - 1;
  int kr0, kr1, nr; float wr0, wr1;
  if (dr < 0)       { kr0 = 0; wr0 = 1.f; kr1 = 0; wr1 = 0.f; nr = 1; }
  else if (dr == 0) { kr0 = 1; wr0 = .5f; kr1 = 2; wr1 = .5f; nr = 2; }
  else              { kr0 = 3; wr0 = 1.f; kr1 = 0; wr1 = 0.f; nr = 1; }
  int kc0, kc1, nc; float wc0, wc1;
  if (dc < 0)       { kc0 = 0; wc0 = 1.f; kc1 = 0; wc1 = 0.f; nc = 1; }
  else if (dc == 0) { kc0 = 1; wc0 = .5f; kc1 = 2; wc1 = .5f; nc = 2; }
  else              { kc0 = 3; wc0 = 1.f; kc1 = 0; wc1 = 0.f; nc = 1; }
  float acc = wr0 * wc0 * W[(kr0 * 4 + kc0) * stride + off];
  if (nc == 2) acc += wr0 * wc1 * W[(kr0 * 4 + kc1) * stride + off];
  if (nr == 2) {
    acc += wr1 * wc0 * W[(kr1 * 4 + kc0) * stride + off];
    if (nc == 2) acc += wr1 * wc1 * W[(kr1 * 4 + kc1) * stride + off];
  }
  return acc;
}

// k-position permutation inside each 32-chunk caused by paired-u32 epilogues
__device__ inline int kperm32(int p) { return (p >> 1) + ((p & 1) << 4); }

// ============ ONE cooperative kernel: pack -> conv -> fc1 -> fc2 ============
// 256 blocks x 1024 threads, dynamic LDS 125696 B -> exactly 1 block/CU.
// Conv phase is the R8-benched conv_mega body verbatim (64 VGPR, no spill;
// weight fragments loaded INSIDE their phase - R7 lesson).
__global__ __launch_bounds__(1024, 4) void fused_all(
    const float* __restrict__ x,
    const float* __restrict__ W1, const float* __restrict__ W2, const float* __restrict__ rt2,
    const float* __restrict__ W3, const float* __restrict__ rt3,
    const float* __restrict__ W4, const float* __restrict__ rt4,
    const float* __restrict__ fcW,
    float* __restrict__ wf1, u16* __restrict__ wp2, u16* __restrict__ wp3,
    u16* __restrict__ wp4, u16* __restrict__ wfc,
    const float* __restrict__ rt1, const float* __restrict__ b1,
    const float* __restrict__ b2, const float* __restrict__ b3,
    const float* __restrict__ b4, const float* __restrict__ fc1b,
    const float* __restrict__ fc2W, const float* __restrict__ fc2b,
    u16* __restrict__ A6, u16* __restrict__ h, float* __restrict__ out) {
  extern __shared__ char smem[];
  cg::grid_group grid = cg::this_grid();

  int blk = blockIdx.x, tid = threadIdx.x;
  int lane = tid & 63, wid = tid >> 6;

  // ---------------- Phase P: pack ----------------
  if (blk < 98) {                      // fc1W transpose-pack slab q = blk
    u16* T = (u16*)smem;               // [32][514] u16 = 32896 B
    int q = blk;
#pragma unroll
    for (int i = 0; i < 4; ++i) {      // 4 x 1024thr x float4 = 16384 f32
      int idx = i * 4096 + tid * 4;
      int k = idx >> 9, n = idx & 511;
      float4 v = *reinterpret_cast<const float4*>(fcW + (size_t)(q * 32 + k) * 512 + n);
      T[k * 514 + n]     = f2bf(v.x);
      T[k * 514 + n + 1] = f2bf(v.y);
      T[k * 514 + n + 2] = f2bf(v.z);
      T[k * 514 + n + 3] = f2bf(v.w);
    }
    __syncthreads();
#pragma unroll
    for (int w = 0; w < 2; ++w) {      // 2 x 1024 = 2048 fragment-writes
      int g = w * 1024 + tid;
      int nt = g >> 6, l = g & 63;
      union { int4 q4; u16 s[8]; } R;
#pragma unroll
      for (int j = 0; j < 8; ++j)      // natural k (A6 natural layout)
        R.s[j] = T[((l >> 4) * 8 + j) * 514 + nt * 16 + (l & 15)];
      *reinterpret_cast<int4*>(wfc + ((size_t)(q * 32 + nt) * 64 + l) * 8) = R.q4;
    }
  } else {                             // small packs
    int idx = (blk - 98) * 1024 + tid; // covers 0..161791 >= 64768
    if (idx < 256) {
      int d = idx >> 5, o = idx & 31;
      wf1[idx] = weff_val(W1, d, o, 32);
    } else if (idx < 9472) {           // wp2: CT=2 KQ=1 (natural k)
      int local = idx - 256;
      int j = local & 7, l = (local >> 3) & 63, chunk = local >> 9;
      int ct = chunk & 1, tap = chunk >> 1;
      int k = (l >> 4) * 8 + j, n = ct * 16 + (l & 15);
      float v = tap < 8 ? weff_val(W2, tap, k * 32 + n, 1024) : rt2[k * 32 + n];
      wp2[local] = f2bf(v);
    } else if (idx < 27904) {          // wp3: CT=4 KQ=1 (perm'd k: H3 paired)
      int local = idx - 9472;
      int j = local & 7, l = (local >> 3) & 63, chunk = local >> 9;
      int ct = chunk & 3, tap = chunk >> 2;
      int k = kperm32((l >> 4) * 8 + j), n = ct * 16 + (l & 15);
      float v = tap < 8 ? weff_val(W3, tap, k * 64 + n, 2048) : rt3[k * 64 + n];
      wp3[local] = f2bf(v);
    } else if (idx < 64768) {          // wp4: CT=4 KQ=2 (perm'd k: H4 paired)
      int local = idx - 27904;
      int j = local & 7, l = (local >> 3) & 63, chunk = local >> 9;
      int q = chunk & 1, tmp = chunk >> 1;
      int ct = tmp & 3, tap = tmp >> 2;
      int k = q * 32 + kperm32((l >> 4) * 8 + j), n = ct * 16 + (l & 15);
      float v = tap < 8 ? weff_val(W4, tap, k * 64 + n, 4096) : rt4[k * 64 + n];
      wp4[local] = f2bf(v);
    }
  }
  __threadfence();
  grid.sync();

  // ---------------- Phase C: conv (R8 conv_mega body, img = blk) ----------------
  {
    int4* H1 = (int4*)smem;
    int4* H3 = (int4*)smem;
    u16*  H5 = (u16*)(smem + 17408);
    int4* H4 = (int4*)(smem + 42496);
    unsigned* H4u = (unsigned*)(smem + 42496);
    float* XT = (float*)(smem + 61568);
    int4*     H2 = (int4*)(smem + 75520);
    unsigned* H2u = (unsigned*)(smem + 75520);

    int img = blk;
    int kcb = lane >> 4, n0 = lane & 15;
    int4 z4 = make_int4(0, 0, 0, 0);
    f32x4 zz = {0.f, 0.f, 0.f, 0.f};

    // phase A: zero H1 (incl pads) + build padded XT
    for (int i = tid; i < 3848; i += 1024) H1[i] = z4;
    if (tid < 960) {
      int r = tid >> 5, c = tid & 31;
      bool in = (r >= 1) && (r <= 28) && (c >= 1) && (c <= 28);
      XT[tid] = in ? x[(size_t)img * 784 + (r - 1) * 28 + (c - 1)] : 0.f;
    }
    __syncthreads();

    // conv1 (Cin=1, fp32) -> H1 bf16 chunks
    if (tid < 784) {
      int px = tid;
      int r = px / 28, c = px - 28 * (px / 28);
      float acc[32];
#pragma unroll
      for (int o = 0; o < 32; ++o) acc[o] = 0.f;
#pragma unroll
      for (int d = 0; d < 8; ++d) {
        float xv = XT[(r + 1 - DRS[d]) * 32 + (c + 1 - DCS[d])];
#pragma unroll
        for (int o = 0; o < 32; ++o) acc[o] = fmaf(xv, wf1[d * 32 + o], acc[o]);
      }
      float inv = 1.f / (float)((3 - (r == 0) - (r == 27)) * (3 - (c == 0) - (c == 27)) - 1);
      float xc = XT[(r + 1) * 32 + c + 1];
      unsigned pk[16];
#pragma unroll
      for (int hh = 0; hh < 16; ++hh)
        pk[hh] = pk2(eluf(acc[2 * hh] * inv + xc * rt1[2 * hh] + b1[2 * hh]),
                     eluf(acc[2 * hh + 1] * inv + xc * rt1[2 * hh + 1] + b1[2 * hh + 1]));
#pragma unroll
      for (int kc = 0; kc < 4; ++kc)
        H1[kc * 962 + (r + 1) * 32 + (c + 1)] =
            make_int4(pk[4 * kc], pk[4 * kc + 1], pk[4 * kc + 2], pk[4 * kc + 3]);
    }
    __syncthreads();

    // conv2 (32->32, MFMA, NCT=2 shared-A): 16 waves x 49 tiles
    {
      bf16x8 w2[9][2];
#pragma unroll
      for (int tap = 0; tap < 9; ++tap)
#pragma unroll
        for (int ct = 0; ct < 2; ++ct)
          w2[tap][ct] = *(const bf16x8*)(wp2 + (tap * 2 + ct) * 512 + lane * 8);
      for (int t = wid; t < 49; t += 16) {
        int pxm = t * 16 + n0;
        int r = pxm / 28, c = pxm - 28 * (pxm / 28);
        f32x4 an[2] = {zz, zz}, ar[2] = {zz, zz};
#pragma unroll
        for (int d = 0; d < 8; ++d) {
          bf16x8 a = *(const bf16x8*)&H1[kcb * 962 + (r + 1 - DRS[d]) * 32 + (c + 1 - DCS[d])];
          an[0] = __builtin_amdgcn_mfma_f32_16x16x32_bf16(a, w2[d][0], an[0], 0, 0, 0);
          an[1] = __builtin_amdgcn_mfma_f32_16x16x32_bf16(a, w2[d][1], an[1], 0, 0, 0);
        }
        {
          bf16x8 a = *(const bf16x8*)&H1[kcb * 962 + (r + 1) * 32 + (c + 1)];
          ar[0] = __builtin_amdgcn_mfma_f32_16x16x32_bf16(a, w2[8][0], ar[0], 0, 0, 0);
          ar[1] = __builtin_amdgcn_mfma_f32_16x16x32_bf16(a, w2[8][1], ar[1], 0, 0, 0);
        }
#pragma unroll
        for (int j = 0; j < 4; ++j) {
          int pm = t * 16 + (lane >> 4) * 4 + j;
          int rm = pm / 28, cm = pm - 28 * (pm / 28);
          float inv = 1.f / (float)((3 - (rm == 0) - (rm == 27)) * (3 - (cm == 0) - (cm == 27)) - 1);
          H2u[pm * 16 + n0] = pk2(eluf(an[0][j] * inv + ar[0][j] + b2[n0]),
                                  eluf(an[1][j] * inv + ar[1][j] + b2[16 + n0]));
        }
      }
    }
    __syncthreads();

    // pool0: H2 -> H3 padded (pads = 0); zero H4 pads concurrently
    for (int i = tid; i < 1032; i += 1024) {
      int kc = i & 3, rem = i >> 2;
      int4 v = z4;
      if (rem < 256) {
        int pr = rem >> 4, pc = rem & 15;
        if (pr >= 1 && pr <= 14 && pc >= 1 && pc <= 14) {
          int px0 = (2 * (pr - 1)) * 28 + 2 * (pc - 1);
          union { int4 q; u16 s[8]; } A, B, C, D, R;
          A.q = H2[px0 * 4 + kc]; B.q = H2[(px0 + 1) * 4 + kc];
          C.q = H2[(px0 + 28) * 4 + kc]; D.q = H2[(px0 + 29) * 4 + kc];
#pragma unroll
          for (int e = 0; e < 8; ++e)
            R.s[e] = f2bf(fmaxf(fmaxf(bf2f(A.s[e]), bf2f(B.s[e])),
                                fmaxf(bf2f(C.s[e]), bf2f(D.s[e]))));
          v = R.q;
        }
      }
      H3[kc * 258 + rem] = v;
    }
    for (int i = tid; i < 2064; i += 1024) H4[i] = z4;
    __syncthreads();

    // conv3 (32->64, MFMA, NCT=2 shared-A): 2 ct-groups x 8 strides
    {
      int ct0 = wid & 1, t0 = wid >> 1;
      bf16x8 w3[9][2];
#pragma unroll
      for (int tap = 0; tap < 9; ++tap)
#pragma unroll
        for (int cc = 0; cc < 2; ++cc)
          w3[tap][cc] = *(const bf16x8*)(wp3 + (tap * 4 + ct0 * 2 + cc) * 512 + lane * 8);
      for (int t = t0; t < 13; t += 8) {
        int pxm = t * 16 + n0; if (pxm > 195) pxm = 195;
        int r = pxm / 14, c = pxm - 14 * (pxm / 14);
        f32x4 an[2] = {zz, zz}, ar[2] = {zz, zz};
#pragma unroll
        for (int d = 0; d < 8; ++d) {
          bf16x8 a = *(const bf16x8*)&H3[kcb * 258 + (r + 1 - DRS[d]) * 16 + (c + 1 - DCS[d])];
          an[0] = __builtin_amdgcn_mfma_f32_16x16x32_bf16(a, w3[d][0], an[0], 0, 0, 0);
          an[1] = __builtin_amdgcn_mfma_f32_16x16x32_bf16(a, w3[d][1], an[1], 0, 0, 0);
        }
        {
          bf16x8 a = *(const bf16x8*)&H3[kcb * 258 + (r + 1) * 16 + (c + 1)];
          ar[0] = __builtin_amdgcn_mfma_f32_16x16x32_bf16(a, w3[8][0], ar[0], 0, 0, 0);
          ar[1] = __builtin_amdgcn_mfma_f32_16x16x32_bf16(a, w3[8][1], ar[1], 0, 0, 0);
        }
#pragma unroll
        for (int j = 0; j < 4; ++j) {
          int pm = t * 16 + (lane >> 4) * 4 + j;
          if (pm < 196) {
            int rm = pm / 14, cm = pm - 14 * (pm / 14);
            float inv = 1.f / (float)((3 - (rm == 0) - (rm == 13)) * (3 - (cm == 0) - (cm == 13)) - 1);
            unsigned v = pk2(eluf(an[0][j] * inv + ar[0][j] + b3[ct0 * 32 + n0]),
                             eluf(an[1][j] * inv + ar[1][j] + b3[ct0 * 32 + 16 + n0]));
            H4u[((ct0 * 4 + (n0 >> 2)) * 258 + (rm + 1) * 16 + (cm + 1)) * 4 + (n0 & 3)] = v;
          }
        }
      }
    }
    __syncthreads();

    // conv4 (64->64, MFMA, NCT=1, weights resident once)
    {
      int ctg = wid & 3, t0 = wid >> 2;
      bf16x8 w4[9][2];
#pragma unroll
      for (int tap = 0; tap < 9; ++tap)
#pragma unroll
        for (int kq = 0; kq < 2; ++kq)
          w4[tap][kq] = *(const bf16x8*)(wp4 + ((tap * 4 + ctg) * 2 + kq) * 512 + lane * 8);
      for (int t = t0; t < 13; t += 4) {
        int pxm = t * 16 + n0; if (pxm > 195) pxm = 195;
        int r = pxm / 14, c = pxm - 14 * (pxm / 14);
        f32x4 an = zz, ar = zz;
#pragma unroll
        for (int d = 0; d < 8; ++d) {
          int rr = r + 1 - DRS[d], c2 = c + 1 - DCS[d];
#pragma unroll
          for (int kq = 0; kq < 2; ++kq) {
            bf16x8 a = *(const bf16x8*)&H4[(kq * 4 + kcb) * 258 + rr * 16 + c2];
            an = __builtin_amdgcn_mfma_f32_16x16x32_bf16(a, w4[d][kq], an, 0, 0, 0);
          }
        }
#pragma unroll
        for (int kq = 0; kq < 2; ++kq) {
          bf16x8 a = *(const bf16x8*)&H4[(kq * 4 + kcb) * 258 + (r + 1) * 16 + (c + 1)];
          ar = __builtin_amdgcn_mfma_f32_16x16x32_bf16(a, w4[8][kq], ar, 0, 0, 0);
        }
#pragma unroll
        for (int j = 0; j < 4; ++j) {
          int pm = t * 16 + (lane >> 4) * 4 + j;
          if (pm < 196) {
            int rm = pm / 14, cm = pm - 14 * (pm / 14);
            float inv = 1.f / (float)((3 - (rm == 0) - (rm == 13)) * (3 - (cm == 0) - (cm == 13)) - 1);
            int n = ctg * 16 + n0;
            H5[pm * 64 + n] = f2bf(eluf(an[j] * inv + ar[j] + b4[n]));
          }
        }
      }
    }
    __syncthreads();

    // pool1: H5 [196][64] -> global A6 [img][49*64] bf16
    if (tid < 392) {
      int kc = tid & 7, q = tid >> 3;
      int r2 = q / 7, c2 = q - 7 * (q / 7);
      int px0 = (2 * r2) * 14 + 2 * c2;
      union { int4 q4; u16 s[8]; } A, B, C, D, R;
      A.q4 = *(const int4*)&H5[px0 * 64 + kc * 8];
      B.q4 = *(const int4*)&H5[(px0 + 1) * 64 + kc * 8];
      C.q4 = *(const int4*)&H5[(px0 + 14) * 64 + kc * 8];
      D.q4 = *(const int4*)&H5[(px0 + 15) * 64 + kc * 8];
#pragma unroll
      for (int e = 0; e < 8; ++e)
        R.s[e] = f2bf(fmaxf(fmaxf(bf2f(A.s[e]), bf2f(B.s[e])),
                            fmaxf(bf2f(C.s[e]), bf2f(D.s[e]))));
      *(int4*)(A6 + ((size_t)img * 49 + q) * 64 + kc * 8) = R.q4;
    }
  }
  __threadfence();
  grid.sync();

  // ---------------- Phase F1: fc1 (MFMA, ks-split 7 x 2 halves) ----------------
  {
    f32x4* LDSf = (f32x4*)smem;        // 14 waves x 64 lanes x 16B = 14336 B
    int mt = blk >> 4, nt2 = blk & 15;
    if (wid < 14) {
      int ks = wid % 7, half = wid / 7;
      int NT = nt2 * 2 + half;
      f32x4 acc = {0.f, 0.f, 0.f, 0.f};
      const u16* Ab = A6 + (size_t)(mt * 16 + (lane & 15)) * 3136 + ks * 448 + (lane >> 4) * 8;
      const u16* Bb = wfc + ((size_t)(ks * 14) * 32 + NT) * 512 + (size_t)lane * 8;
#pragma unroll
      for (int qq = 0; qq < 14; ++qq) {
        bf16x8 a = *(const bf16x8*)(Ab + qq * 32);
        bf16x8 b = *(const bf16x8*)(Bb + (size_t)qq * 16384);
        acc = __builtin_amdgcn_mfma_f32_16x16x32_bf16(a, b, acc, 0, 0, 0);
      }
      LDSf[wid * 64 + lane] = acc;
    }
    __syncthreads();
    if (wid < 2) {
      int NT = nt2 * 2 + wid;
      f32x4 s = LDSf[(wid * 7) * 64 + lane];
#pragma unroll
      for (int ks = 1; ks < 7; ++ks) {
        f32x4 p = LDSf[(wid * 7 + ks) * 64 + lane];
#pragma unroll
        for (int j = 0; j < 4; ++j) s[j] += p[j];
      }
#pragma unroll
      for (int j = 0; j < 4; ++j) {
        int row = mt * 16 + (lane >> 4) * 4 + j;
        int col = NT * 16 + (lane & 15);
        h[(size_t)row * 512 + col] = f2bf(eluf(s[j] + fc1b[col]));
      }
    }
  }
  __threadfence();
  grid.sync();

  // ---------------- Phase F2: fc2 + log_softmax (wave 0, row = blk) ----------------
  if (tid < 64) {
    int bb = blk;
    int t = tid;
    float acc[10];
#pragma unroll
    for (int o = 0; o < 10; ++o) acc[o] = 0.f;
    bf16x8 hv = *(const bf16x8*)(h + (size_t)bb * 512 + t * 8);
#pragma unroll
    for (int kk = 0; kk < 8; ++kk) {
      float xv = bf2f((u16)hv[kk]);
      int k = t * 8 + kk;
#pragma unroll
      for (int o = 0; o < 10; ++o) acc[o] = fmaf(xv, fc2W[k * 10 + o], acc[o]);
    }
#pragma unroll
    for (int o = 0; o < 10; ++o) {
      float v = acc[o];
#pragma unroll
      for (int s = 32; s >= 1; s >>= 1) v += __shfl_xor(v, s);
      acc[o] = v + fc2b[o];
    }
    float m = acc[0];
#pragma unroll
    for (int o = 1; o < 10; ++o) m = fmaxf(m, acc[o]);
    float sum = 0.f;
#pragma unroll
    for (int o = 0; o < 10; ++o) sum += __expf(acc[o] - m);
    float lse = m + __logf(sum);
    if (t < 10) out[bb * 10 + t] = acc[t] - lse;
  }
}

extern "C" void kernel_launch(void* const* d_in, const int* in_sizes, int n_in,
                              void* d_out, int out_size, void* d_ws, size_t ws_size,
                              hipStream_t stream) {
  const float* x    = (const float*)d_in[0];
  const float* W1   = (const float*)d_in[7];
  const float* r1   = (const float*)d_in[8];
  const float* b1   = (const float*)d_in[9];
  const float* W2   = (const float*)d_in[10];
  const float* r2   = (const float*)d_in[11];
  const float* b2   = (const float*)d_in[12];
  const float* W3   = (const float*)d_in[13];
  const float* r3   = (const float*)d_in[14];
  const float* b3   = (const float*)d_in[15];
  const float* W4   = (const float*)d_in[16];
  const float* r4   = (const float*)d_in[17];
  const float* b4   = (const float*)d_in[18];
  const float* fc1W = (const float*)d_in[19];
  const float* fc1b = (const float*)d_in[20];
  const float* fc2W = (const float*)d_in[21];
  const float* fc2b = (const float*)d_in[22];

  char* wsb = (char*)d_ws;
  float* wf1  = (float*)(wsb + 0);        // 1024 B
  u16*   wp2  = (u16*)(wsb + 1024);       // 18432 B
  u16*   wp3  = (u16*)(wsb + 19456);      // 36864 B
  u16*   wp4  = (u16*)(wsb + 56320);      // 73728 B
  u16*   wfc  = (u16*)(wsb + 130048);     // 3211264 B
  u16*   A6   = (u16*)(wsb + 3341312);    // 1605632 B  [256][3136] bf16
  u16*   hbuf = (u16*)(wsb + 4946944);    // 262144 B   [256][512] bf16
  float* outp = (float*)d_out;

  (void)hipFuncSetAttribute((const void*)fused_all,
                            hipFuncAttributeMaxDynamicSharedMemorySize, 125696);

  void* params[] = {
      (void*)&x,   (void*)&W1, (void*)&W2, (void*)&r2, (void*)&W3, (void*)&r3,
      (void*)&W4,  (void*)&r4, (void*)&fc1W,
      (void*)&wf1, (void*)&wp2, (void*)&wp3, (void*)&wp4, (void*)&wfc,
      (void*)&r1,  (void*)&b1, (void*)&b2, (void*)&b3, (void*)&b4,
      (void*)&fc1b, (void*)&fc2W, (void*)&fc2b,
      (void*)&A6,  (void*)&hbuf, (void*)&outp};

  (void)hipLaunchCooperativeKernel((const void*)fused_all, dim3(256), dim3(1024),
                                   params, 125696, stream);
}

// Round 11
// 70.036 us; speedup vs baseline: 5.5428x; 5.5428x over previous
//
#include <hip/hip_runtime.h>

typedef unsigned short u16;
typedef short bf16x8 __attribute__((ext_vector_type(8)));   // 8 bf16 in 4 VGPRs
typedef float f32x4 __attribute__((ext_vector_type(4)));

__device__ __constant__ const int DRS[8] = {-1,-1,-1, 0, 0, 1, 1, 1};
__device__ __constant__ const int DCS[8] = {-1, 0, 1,-1, 1,-1, 0, 1};

__device__ inline float bf2f(u16 u) { return __uint_as_float(((unsigned)u) << 16); }
__device__ inline u16 f2bf(float f) {            // round-to-nearest-even
  unsigned u = __float_as_uint(f);
  return (u16)((u + 0x7fffu + ((u >> 16) & 1u)) >> 16);
}
__device__ inline float eluf(float v) { return v > 0.f ? v : (__expf(v) - 1.f); }
__device__ inline unsigned pk2(float a, float b) {
  return (unsigned)f2bf(a) | ((unsigned)f2bf(b) << 16);
}

// collapse degree-1 B-spline weights for grid direction d (0..7, center skipped)
__device__ inline float weff_val(const float* __restrict__ W, int d, int off, int stride) {
  int dd = d >= 4 ? d + 1 : d;
  int dr = dd / 3 - 1, dc = dd - (dd / 3) * 3 - 1;
  int kr0, kr1, nr; float wr0, wr1;
  if (dr < 0)       { kr0 = 0; wr0 = 1.f; kr1 = 0; wr1 = 0.f; nr = 1; }
  else if (dr == 0) { kr0 = 1; wr0 = .5f; kr1 = 2; wr1 = .5f; nr = 2; }
  else              { kr0 = 3; wr0 = 1.f; kr1 = 0; wr1 = 0.f; nr = 1; }
  int kc0, kc1, nc; float wc0, wc1;
  if (dc < 0)       { kc0 = 0; wc0 = 1.f; kc1 = 0; wc1 = 0.f; nc = 1; }
  else if (dc == 0) { kc0 = 1; wc0 = .5f; kc1 = 2; wc1 = .5f; nc = 2; }
  else              { kc0 = 3; wc0 = 1.f; kc1 = 0; wc1 = 0.f; nc = 1; }
  float acc = wr0 * wc0 * W[(kr0 * 4 + kc0) * stride + off];
  if (nc == 2) acc += wr0 * wc1 * W[(kr0 * 4 + kc1) * stride + off];
  if (nr == 2) {
    acc += wr1 * wc0 * W[(kr1 * 4 + kc0) * stride + off];
    if (nc == 2) acc += wr1 * wc1 * W[(kr1 * 4 + kc1) * stride + off];
  }
  return acc;
}

// k-position permutation inside each 32-chunk caused by paired-u32 epilogues:
// storage pos p holds channel (p>>1) + 16*(p&1)
__device__ inline int kperm32(int p) { return (p >> 1) + ((p & 1) << 4); }

// ---- pack kernel: blocks 0..97 = fc1W LDS-transpose; blocks 98.. = small packs
__global__ __launch_bounds__(256) void pack_all(
    const float* __restrict__ W1,
    const float* __restrict__ W2, const float* __restrict__ rt2,
    const float* __restrict__ W3, const float* __restrict__ rt3,
    const float* __restrict__ W4, const float* __restrict__ rt4,
    const float* __restrict__ fcW,
    float* __restrict__ wf1, u16* __restrict__ wp2,
    u16* __restrict__ wp3, u16* __restrict__ wp4, u16* __restrict__ wfc) {
  __shared__ u16 T[32 * 514];
  int blk = blockIdx.x, t = threadIdx.x;
  if (blk < 98) {              // fc1W transpose-pack: q-slab = rows 32q..32q+31
    int q = blk;
#pragma unroll
    for (int i = 0; i < 16; ++i) {               // coalesced float4 reads
      int idx = i * 1024 + t * 4;
      int k = idx >> 9, n = idx & 511;
      float4 v = *reinterpret_cast<const float4*>(fcW + (size_t)(q * 32 + k) * 512 + n);
      T[k * 514 + n]     = f2bf(v.x);
      T[k * 514 + n + 1] = f2bf(v.y);
      T[k * 514 + n + 2] = f2bf(v.z);
      T[k * 514 + n + 3] = f2bf(v.w);
    }
    __syncthreads();
#pragma unroll
    for (int w = 0; w < 8; ++w) {                // coalesced 16B fragment writes
      int g = w * 256 + t;
      int nt = g >> 6, l = g & 63;
      union { int4 q4; u16 s[8]; } R;
#pragma unroll
      for (int j = 0; j < 8; ++j)                // natural k (A6 natural layout)
        R.s[j] = T[((l >> 4) * 8 + j) * 514 + nt * 16 + (l & 15)];
      *reinterpret_cast<int4*>(wfc + ((size_t)(q * 32 + nt) * 64 + l) * 8) = R.q4;
    }
    return;
  }
  int idx = (blk - 98) * 256 + t;                // small packs (< 64768)
  if (idx < 256) {                               // weff1 fp32 [8][32]
    int d = idx >> 5, o = idx & 31;
    wf1[idx] = weff_val(W1, d, o, 32);
    return;
  }
  if (idx < 9472) {                              // wp2: CT=2 KQ=1 (natural k)
    int local = idx - 256;
    int j = local & 7, l = (local >> 3) & 63, chunk = local >> 9;
    int ct = chunk & 1, tap = chunk >> 1;
    int k = (l >> 4) * 8 + j, n = ct * 16 + (l & 15);
    float v = tap < 8 ? weff_val(W2, tap, k * 32 + n, 1024) : rt2[k * 32 + n];
    wp2[local] = f2bf(v);
    return;
  }
  if (idx < 27904) {                             // wp3: CT=4 KQ=1 (perm'd k: H3 paired)
    int local = idx - 9472;
    int j = local & 7, l = (local >> 3) & 63, chunk = local >> 9;
    int ct = chunk & 3, tap = chunk >> 2;
    int k = kperm32((l >> 4) * 8 + j), n = ct * 16 + (l & 15);
    float v = tap < 8 ? weff_val(W3, tap, k * 64 + n, 2048) : rt3[k * 64 + n];
    wp3[local] = f2bf(v);
    return;
  }
  if (idx < 64768) {                             // wp4: CT=4 KQ=2 (perm'd k: H4 paired)
    int local = idx - 27904;
    int j = local & 7, l = (local >> 3) & 63, chunk = local >> 9;
    int q = chunk & 1, tmp = chunk >> 1;
    int ct = tmp & 3, tap = tmp >> 2;
    int k = q * 32 + kperm32((l >> 4) * 8 + j), n = ct * 16 + (l & 15);
    float v = tap < 8 ? weff_val(W4, tap, k * 64 + n, 4096) : rt4[k * 64 + n];
    wp4[local] = f2bf(v);
  }
}

// ---- mega conv kernel: block = 1 image (1024 thr, 16 waves), LDS-resident ---
// R8-benched configuration except conv4: now NCT=2 with tap-inner weight
// reload (~40 live VGPRs; halves conv4's A-fragment LDS reads 936->468 KB).
// Weight fragments loaded INSIDE their phase (R7 lesson: never hoist).
// LDS (bytes), temporally overlapped:
//   early : H1 [0,61568) 4 grp stride 962 int4 | XT [61568,65408) f32 30x32
//   mid   : H2 [75520,125696) [784][16] u32 (paired couts)
//   late  : H3 [0,16512) 4 grp stride 258 int4 | H4 [42496,75520) 8 grp stride 258
//           H5 [17408,42496) [196][64] u16 (natural)
__global__ __launch_bounds__(1024, 4) void conv_mega(
    const float* __restrict__ x,
    const float* __restrict__ wf1, const float* __restrict__ rt1, const float* __restrict__ b1,
    const u16* __restrict__ wp2, const float* __restrict__ b2,
    const u16* __restrict__ wp3, const float* __restrict__ b3,
    const u16* __restrict__ wp4, const float* __restrict__ b4,
    u16* __restrict__ A6) {
  extern __shared__ char smem[];
  int4* H1 = (int4*)smem;
  int4* H3 = (int4*)smem;
  u16*  H5 = (u16*)(smem + 17408);
  int4* H4 = (int4*)(smem + 42496);
  unsigned* H4u = (unsigned*)(smem + 42496);
  float* XT = (float*)(smem + 61568);
  int4*     H2 = (int4*)(smem + 75520);
  unsigned* H2u = (unsigned*)(smem + 75520);

  int img = blockIdx.x, tid = threadIdx.x;
  int lane = tid & 63, wid = tid >> 6;
  int kcb = lane >> 4, n0 = lane & 15;
  int4 z4 = make_int4(0, 0, 0, 0);
  f32x4 zz = {0.f, 0.f, 0.f, 0.f};

  // phase A: zero H1 (incl pads) + build padded XT
  for (int i = tid; i < 3848; i += 1024) H1[i] = z4;
  if (tid < 960) {
    int r = tid >> 5, c = tid & 31;
    bool in = (r >= 1) && (r <= 28) && (c >= 1) && (c <= 28);
    XT[tid] = in ? x[(size_t)img * 784 + (r - 1) * 28 + (c - 1)] : 0.f;
  }
  __syncthreads();

  // ---- conv1 (Cin=1, fp32) -> H1 bf16 chunks ----
  if (tid < 784) {
    int px = tid;
    int r = px / 28, c = px - 28 * (px / 28);
    float acc[32];
#pragma unroll
    for (int o = 0; o < 32; ++o) acc[o] = 0.f;
#pragma unroll
    for (int d = 0; d < 8; ++d) {
      float xv = XT[(r + 1 - DRS[d]) * 32 + (c + 1 - DCS[d])];
#pragma unroll
      for (int o = 0; o < 32; ++o) acc[o] = fmaf(xv, wf1[d * 32 + o], acc[o]);
    }
    float inv = 1.f / (float)((3 - (r == 0) - (r == 27)) * (3 - (c == 0) - (c == 27)) - 1);
    float xc = XT[(r + 1) * 32 + c + 1];
    unsigned pk[16];
#pragma unroll
    for (int h = 0; h < 16; ++h)
      pk[h] = pk2(eluf(acc[2 * h] * inv + xc * rt1[2 * h] + b1[2 * h]),
                  eluf(acc[2 * h + 1] * inv + xc * rt1[2 * h + 1] + b1[2 * h + 1]));
#pragma unroll
    for (int kc = 0; kc < 4; ++kc)
      H1[kc * 962 + (r + 1) * 32 + (c + 1)] =
          make_int4(pk[4 * kc], pk[4 * kc + 1], pk[4 * kc + 2], pk[4 * kc + 3]);
  }
  __syncthreads();

  // ---- conv2 (32->32, MFMA, NCT=2 shared-A): 16 waves x 49 tiles ----
  {
    bf16x8 w2[9][2];
#pragma unroll
    for (int tap = 0; tap < 9; ++tap)
#pragma unroll
      for (int ct = 0; ct < 2; ++ct)
        w2[tap][ct] = *(const bf16x8*)(wp2 + (tap * 2 + ct) * 512 + lane * 8);
    for (int t = wid; t < 49; t += 16) {
      int pxm = t * 16 + n0;
      int r = pxm / 28, c = pxm - 28 * (pxm / 28);
      f32x4 an[2] = {zz, zz}, ar[2] = {zz, zz};
#pragma unroll
      for (int d = 0; d < 8; ++d) {
        bf16x8 a = *(const bf16x8*)&H1[kcb * 962 + (r + 1 - DRS[d]) * 32 + (c + 1 - DCS[d])];
        an[0] = __builtin_amdgcn_mfma_f32_16x16x32_bf16(a, w2[d][0], an[0], 0, 0, 0);
        an[1] = __builtin_amdgcn_mfma_f32_16x16x32_bf16(a, w2[d][1], an[1], 0, 0, 0);
      }
      {
        bf16x8 a = *(const bf16x8*)&H1[kcb * 962 + (r + 1) * 32 + (c + 1)];
        ar[0] = __builtin_amdgcn_mfma_f32_16x16x32_bf16(a, w2[8][0], ar[0], 0, 0, 0);
        ar[1] = __builtin_amdgcn_mfma_f32_16x16x32_bf16(a, w2[8][1], ar[1], 0, 0, 0);
      }
#pragma unroll
      for (int j = 0; j < 4; ++j) {
        int pm = t * 16 + (lane >> 4) * 4 + j;
        int rm = pm / 28, cm = pm - 28 * (pm / 28);
        float inv = 1.f / (float)((3 - (rm == 0) - (rm == 27)) * (3 - (cm == 0) - (cm == 27)) - 1);
        H2u[pm * 16 + n0] = pk2(eluf(an[0][j] * inv + ar[0][j] + b2[n0]),
                                eluf(an[1][j] * inv + ar[1][j] + b2[16 + n0]));
      }
    }
  }
  __syncthreads();

  // ---- pool0: H2 -> H3 padded (pads = 0); zero H4 pads concurrently ----
  for (int i = tid; i < 1032; i += 1024) {
    int kc = i & 3, rem = i >> 2;
    int4 v = z4;
    if (rem < 256) {
      int pr = rem >> 4, pc = rem & 15;
      if (pr >= 1 && pr <= 14 && pc >= 1 && pc <= 14) {
        int px0 = (2 * (pr - 1)) * 28 + 2 * (pc - 1);
        union { int4 q; u16 s[8]; } A, B, C, D, R;
        A.q = H2[px0 * 4 + kc]; B.q = H2[(px0 + 1) * 4 + kc];
        C.q = H2[(px0 + 28) * 4 + kc]; D.q = H2[(px0 + 29) * 4 + kc];
#pragma unroll
        for (int e = 0; e < 8; ++e)
          R.s[e] = f2bf(fmaxf(fmaxf(bf2f(A.s[e]), bf2f(B.s[e])),
                              fmaxf(bf2f(C.s[e]), bf2f(D.s[e]))));
        v = R.q;
      }
    }
    H3[kc * 258 + rem] = v;
  }
  for (int i = tid; i < 2064; i += 1024) H4[i] = z4;
  __syncthreads();

  // ---- conv3 (32->64, MFMA, NCT=2 shared-A): 2 ct-groups x 8 strides ----
  {
    int ct0 = wid & 1, t0 = wid >> 1;
    bf16x8 w3[9][2];
#pragma unroll
    for (int tap = 0; tap < 9; ++tap)
#pragma unroll
      for (int cc = 0; cc < 2; ++cc)
        w3[tap][cc] = *(const bf16x8*)(wp3 + (tap * 4 + ct0 * 2 + cc) * 512 + lane * 8);
    for (int t = t0; t < 13; t += 8) {
      int pxm = t * 16 + n0; if (pxm > 195) pxm = 195;
      int r = pxm / 14, c = pxm - 14 * (pxm / 14);
      f32x4 an[2] = {zz, zz}, ar[2] = {zz, zz};
#pragma unroll
      for (int d = 0; d < 8; ++d) {
        bf16x8 a = *(const bf16x8*)&H3[kcb * 258 + (r + 1 - DRS[d]) * 16 + (c + 1 - DCS[d])];
        an[0] = __builtin_amdgcn_mfma_f32_16x16x32_bf16(a, w3[d][0], an[0], 0, 0, 0);
        an[1] = __builtin_amdgcn_mfma_f32_16x16x32_bf16(a, w3[d][1], an[1], 0, 0, 0);
      }
      {
        bf16x8 a = *(const bf16x8*)&H3[kcb * 258 + (r + 1) * 16 + (c + 1)];
        ar[0] = __builtin_amdgcn_mfma_f32_16x16x32_bf16(a, w3[8][0], ar[0], 0, 0, 0);
        ar[1] = __builtin_amdgcn_mfma_f32_16x16x32_bf16(a, w3[8][1], ar[1], 0, 0, 0);
      }
#pragma unroll
      for (int j = 0; j < 4; ++j) {
        int pm = t * 16 + (lane >> 4) * 4 + j;
        if (pm < 196) {
          int rm = pm / 14, cm = pm - 14 * (pm / 14);
          float inv = 1.f / (float)((3 - (rm == 0) - (rm == 13)) * (3 - (cm == 0) - (cm == 13)) - 1);
          unsigned v = pk2(eluf(an[0][j] * inv + ar[0][j] + b3[ct0 * 32 + n0]),
                           eluf(an[1][j] * inv + ar[1][j] + b3[ct0 * 32 + 16 + n0]));
          H4u[((ct0 * 4 + (n0 >> 2)) * 258 + (rm + 1) * 16 + (cm + 1)) * 4 + (n0 & 3)] = v;
        }
      }
    }
  }
  __syncthreads();

  // ---- conv4 (64->64, MFMA, NCT=2, tap-inner weight reload ~40 live VGPR) ----
  // A-fragments shared across the 2 couts of the pair: LDS reads halved vs NCT=1.
  {
    int ct0 = wid & 1, t0 = wid >> 1;
    for (int t = t0; t < 13; t += 8) {
      int pxm = t * 16 + n0; if (pxm > 195) pxm = 195;
      int r = pxm / 14, c = pxm - 14 * (pxm / 14);
      f32x4 an[2] = {zz, zz}, ar[2] = {zz, zz};
#pragma unroll
      for (int d = 0; d < 8; ++d) {
        int rr = r + 1 - DRS[d], c2 = c + 1 - DCS[d];
#pragma unroll
        for (int kq = 0; kq < 2; ++kq) {
          bf16x8 a = *(const bf16x8*)&H4[(kq * 4 + kcb) * 258 + rr * 16 + c2];
          bf16x8 w0 = *(const bf16x8*)(wp4 + ((size_t)((d * 4 + ct0 * 2) * 2 + kq) * 64 + lane) * 8);
          bf16x8 w1 = *(const bf16x8*)(wp4 + ((size_t)((d * 4 + ct0 * 2 + 1) * 2 + kq) * 64 + lane) * 8);
          an[0] = __builtin_amdgcn_mfma_f32_16x16x32_bf16(a, w0, an[0], 0, 0, 0);
          an[1] = __builtin_amdgcn_mfma_f32_16x16x32_bf16(a, w1, an[1], 0, 0, 0);
        }
      }
#pragma unroll
      for (int kq = 0; kq < 2; ++kq) {
        bf16x8 a = *(const bf16x8*)&H4[(kq * 4 + kcb) * 258 + (r + 1) * 16 + (c + 1)];
        bf16x8 w0 = *(const bf16x8*)(wp4 + ((size_t)((8 * 4 + ct0 * 2) * 2 + kq) * 64 + lane) * 8);
        bf16x8 w1 = *(const bf16x8*)(wp4 + ((size_t)((8 * 4 + ct0 * 2 + 1) * 2 + kq) * 64 + lane) * 8);
        ar[0] = __builtin_amdgcn_mfma_f32_16x16x32_bf16(a, w0, ar[0], 0, 0, 0);
        ar[1] = __builtin_amdgcn_mfma_f32_16x16x32_bf16(a, w1, ar[1], 0, 0, 0);
      }
#pragma unroll
      for (int j = 0; j < 4; ++j) {
        int pm = t * 16 + (lane >> 4) * 4 + j;
        if (pm < 196) {
          int rm = pm / 14, cm = pm - 14 * (pm / 14);
          float inv = 1.f / (float)((3 - (rm == 0) - (rm == 13)) * (3 - (cm == 0) - (cm == 13)) - 1);
          int na = ct0 * 32 + n0, nb = ct0 * 32 + 16 + n0;
          H5[pm * 64 + na] = f2bf(eluf(an[0][j] * inv + ar[0][j] + b4[na]));
          H5[pm * 64 + nb] = f2bf(eluf(an[1][j] * inv + ar[1][j] + b4[nb]));
        }
      }
    }
  }
  __syncthreads();

  // ---- pool1: H5 [196][64] u16 natural -> global A6 [img][49*64] bf16 ----
  if (tid < 392) {
    int kc = tid & 7, q = tid >> 3;
    int r2 = q / 7, c2 = q - 7 * (q / 7);
    int px0 = (2 * r2) * 14 + 2 * c2;
    union { int4 q4; u16 s[8]; } A, B, C, D, R;
    A.q4 = *(const int4*)&H5[px0 * 64 + kc * 8];
    B.q4 = *(const int4*)&H5[(px0 + 1) * 64 + kc * 8];
    C.q4 = *(const int4*)&H5[(px0 + 14) * 64 + kc * 8];
    D.q4 = *(const int4*)&H5[(px0 + 15) * 64 + kc * 8];
#pragma unroll
    for (int e = 0; e < 8; ++e)
      R.s[e] = f2bf(fmaxf(fmaxf(bf2f(A.s[e]), bf2f(B.s[e])),
                          fmaxf(bf2f(C.s[e]), bf2f(D.s[e]))));
    *(int4*)(A6 + ((size_t)img * 49 + q) * 64 + kc * 8) = R.q4;
  }
}

// ---- FC1 bf16 MFMA: 256 blocks (16 mt x 16 nt2) x 8 waves, ks-split 4 ------
// wave (ks, half): K-chunk ks (qq groups [0,25,50,74,98]), col-group nt2*2+half.
// Partials LDS-reduced; bias + ELU fused; writes bf16 h[256,512].
__global__ __launch_bounds__(512) void fc1_mfma(
    const u16* __restrict__ A6, const u16* __restrict__ wfc,
    const float* __restrict__ fc1b, u16* __restrict__ h) {
  __shared__ f32x4 red[8][64];
  int blk = blockIdx.x;
  int mt = blk & 15, nt2 = blk >> 4;
  int lane = threadIdx.x & 63, wid = threadIdx.x >> 6;
  int half = wid & 1, ks = wid >> 1;
  int NT = nt2 * 2 + half;
  const int q0 = ks * 25 - ((ks >= 3) ? 1 : 0);            // starts 0,25,50,74
  const int q1 = (ks + 1) * 25 - ((ks >= 2) ? 1 : 0);      // ends   25,50,74,98
  f32x4 acc = {0.f, 0.f, 0.f, 0.f};
  const u16* Ab = A6 + (size_t)(mt * 16 + (lane & 15)) * 3136 + (lane >> 4) * 8;
  for (int qq = q0; qq < q1; ++qq) {
    bf16x8 a = *(const bf16x8*)(Ab + qq * 32);
    bf16x8 b = *(const bf16x8*)(wfc + ((size_t)(qq * 32 + NT) * 64 + lane) * 8);
    acc = __builtin_amdgcn_mfma_f32_16x16x32_bf16(a, b, acc, 0, 0, 0);
  }
  red[wid][lane] = acc;
  __syncthreads();
  if (wid < 2) {                                            // finalize half=wid
    f32x4 s = red[wid][lane];
#pragma unroll
    for (int k2 = 1; k2 < 4; ++k2) {
      f32x4 p = red[k2 * 2 + wid][lane];
#pragma unroll
      for (int j = 0; j < 4; ++j) s[j] += p[j];
    }
    int NTo = nt2 * 2 + wid;
#pragma unroll
    for (int j = 0; j < 4; ++j) {
      int row = mt * 16 + (lane >> 4) * 4 + j;
      int col = NTo * 16 + (lane & 15);
      h[(size_t)row * 512 + col] = f2bf(eluf(s[j] + fc1b[col]));
    }
  }
}

// ---- FC2 (reads bf16 h) + bias + log_softmax -------------------------------
__global__ __launch_bounds__(64) void fc2_kernel(
    const u16* __restrict__ h, const float* __restrict__ W,
    const float* __restrict__ bias, float* __restrict__ out) {
  int bb = blockIdx.x;
  int t = threadIdx.x;
  float acc[10];
#pragma unroll
  for (int o = 0; o < 10; ++o) acc[o] = 0.f;
  bf16x8 hv = *(const bf16x8*)(h + (size_t)bb * 512 + t * 8);
#pragma unroll
  for (int kk = 0; kk < 8; ++kk) {
    float xv = bf2f((u16)hv[kk]);
    int k = t * 8 + kk;
#pragma unroll
    for (int o = 0; o < 10; ++o) acc[o] = fmaf(xv, W[k * 10 + o], acc[o]);
  }
#pragma unroll
  for (int o = 0; o < 10; ++o) {
    float v = acc[o];
#pragma unroll
    for (int s = 32; s >= 1; s >>= 1) v += __shfl_xor(v, s);
    acc[o] = v + bias[o];
  }
  float m = acc[0];
#pragma unroll
  for (int o = 1; o < 10; ++o) m = fmaxf(m, acc[o]);
  float sum = 0.f;
#pragma unroll
  for (int o = 0; o < 10; ++o) sum += __expf(acc[o] - m);
  float lse = m + __logf(sum);
  if (t < 10) out[bb * 10 + t] = acc[t] - lse;
}

extern "C" void kernel_launch(void* const* d_in, const int* in_sizes, int n_in,
                              void* d_out, int out_size, void* d_ws, size_t ws_size,
                              hipStream_t stream) {
  const float* x    = (const float*)d_in[0];
  const float* W1   = (const float*)d_in[7];
  const float* r1   = (const float*)d_in[8];
  const float* b1   = (const float*)d_in[9];
  const float* W2   = (const float*)d_in[10];
  const float* r2   = (const float*)d_in[11];
  const float* b2   = (const float*)d_in[12];
  const float* W3   = (const float*)d_in[13];
  const float* r3   = (const float*)d_in[14];
  const float* b3   = (const float*)d_in[15];
  const float* W4   = (const float*)d_in[16];
  const float* r4   = (const float*)d_in[17];
  const float* b4   = (const float*)d_in[18];
  const float* fc1W = (const float*)d_in[19];
  const float* fc1b = (const float*)d_in[20];
  const float* fc2W = (const float*)d_in[21];
  const float* fc2b = (const float*)d_in[22];

  char* wsb = (char*)d_ws;
  float* wf1  = (float*)(wsb + 0);        // 1024 B
  u16*   wp2  = (u16*)(wsb + 1024);       // 18432 B
  u16*   wp3  = (u16*)(wsb + 19456);      // 36864 B
  u16*   wp4  = (u16*)(wsb + 56320);      // 73728 B
  u16*   wfc  = (u16*)(wsb + 130048);     // 3211264 B
  u16*   A6   = (u16*)(wsb + 3341312);    // 1605632 B  [256][3136] bf16
  u16*   hbuf = (u16*)(wsb + 4946944);    // 262144 B   [256][512] bf16

  pack_all<<<351, 256, 0, stream>>>(W1, W2, r2, W3, r3, W4, r4, fc1W,
                                    wf1, wp2, wp3, wp4, wfc);

  (void)hipFuncSetAttribute((const void*)conv_mega,
                            hipFuncAttributeMaxDynamicSharedMemorySize, 125696);
  conv_mega<<<256, 1024, 125696, stream>>>(x, wf1, r1, b1, wp2, b2, wp3, b3,
                                           wp4, b4, A6);

  fc1_mfma<<<256, 512, 0, stream>>>(A6, wfc, fc1b, hbuf);
  fc2_kernel<<<256, 64, 0, stream>>>(hbuf, fc2W, fc2b, (float*)d_out);
}

// Round 12
// 53.023 us; speedup vs baseline: 7.3213x; 1.3209x over previous
//
#include <hip/hip_runtime.h>

typedef unsigned short u16;
typedef short bf16x8 __attribute__((ext_vector_type(8)));   // 8 bf16 in 4 VGPRs
typedef float f32x4 __attribute__((ext_vector_type(4)));

__device__ __constant__ const int DRS[8] = {-1,-1,-1, 0, 0, 1, 1, 1};
__device__ __constant__ const int DCS[8] = {-1, 0, 1,-1, 1,-1, 0, 1};

__device__ inline float bf2f(u16 u) { return __uint_as_float(((unsigned)u) << 16); }
__device__ inline u16 f2bf(float f) {            // round-to-nearest-even
  unsigned u = __float_as_uint(f);
  return (u16)((u + 0x7fffu + ((u >> 16) & 1u)) >> 16);
}
__device__ inline float eluf(float v) { return v > 0.f ? v : (__expf(v) - 1.f); }
__device__ inline unsigned pk2(float a, float b) {
  return (unsigned)f2bf(a) | ((unsigned)f2bf(b) << 16);
}

// collapse degree-1 B-spline weights for grid direction d (0..7, center skipped)
__device__ inline float weff_val(const float* __restrict__ W, int d, int off, int stride) {
  int dd = d >= 4 ? d + 1 : d;
  int dr = dd / 3 - 1, dc = dd - (dd / 3) * 3 - 1;
  int kr0, kr1, nr; float wr0, wr1;
  if (dr < 0)       { kr0 = 0; wr0 = 1.f; kr1 = 0; wr1 = 0.f; nr = 1; }
  else if (dr == 0) { kr0 = 1; wr0 = .5f; kr1 = 2; wr1 = .5f; nr = 2; }
  else              { kr0 = 3; wr0 = 1.f; kr1 = 0; wr1 = 0.f; nr = 1; }
  int kc0, kc1, nc; float wc0, wc1;
  if (dc < 0)       { kc0 = 0; wc0 = 1.f; kc1 = 0; wc1 = 0.f; nc = 1; }
  else if (dc == 0) { kc0 = 1; wc0 = .5f; kc1 = 2; wc1 = .5f; nc = 2; }
  else              { kc0 = 3; wc0 = 1.f; kc1 = 0; wc1 = 0.f; nc = 1; }
  float acc = wr0 * wc0 * W[(kr0 * 4 + kc0) * stride + off];
  if (nc == 2) acc += wr0 * wc1 * W[(kr0 * 4 + kc1) * stride + off];
  if (nr == 2) {
    acc += wr1 * wc0 * W[(kr1 * 4 + kc0) * stride + off];
    if (nc == 2) acc += wr1 * wc1 * W[(kr1 * 4 + kc1) * stride + off];
  }
  return acc;
}

// k-position permutation inside each 32-chunk caused by paired-u32 epilogues:
// storage pos p holds channel (p>>1) + 16*(p&1)
__device__ inline int kperm32(int p) { return (p >> 1) + ((p & 1) << 4); }

// ---- pack kernel: blocks 0..97 = fc1W LDS-transpose; blocks 98.. = small packs
__global__ __launch_bounds__(256) void pack_all(
    const float* __restrict__ W1,
    const float* __restrict__ W2, const float* __restrict__ rt2,
    const float* __restrict__ W3, const float* __restrict__ rt3,
    const float* __restrict__ W4, const float* __restrict__ rt4,
    const float* __restrict__ fcW,
    float* __restrict__ wf1, u16* __restrict__ wp2,
    u16* __restrict__ wp3, u16* __restrict__ wp4, u16* __restrict__ wfc) {
  __shared__ u16 T[32 * 514];
  int blk = blockIdx.x, t = threadIdx.x;
  if (blk < 98) {              // fc1W transpose-pack: q-slab = rows 32q..32q+31
    int q = blk;
#pragma unroll
    for (int i = 0; i < 16; ++i) {               // coalesced float4 reads
      int idx = i * 1024 + t * 4;
      int k = idx >> 9, n = idx & 511;
      float4 v = *reinterpret_cast<const float4*>(fcW + (size_t)(q * 32 + k) * 512 + n);
      T[k * 514 + n]     = f2bf(v.x);
      T[k * 514 + n + 1] = f2bf(v.y);
      T[k * 514 + n + 2] = f2bf(v.z);
      T[k * 514 + n + 3] = f2bf(v.w);
    }
    __syncthreads();
#pragma unroll
    for (int w = 0; w < 8; ++w) {                // coalesced 16B fragment writes
      int g = w * 256 + t;
      int nt = g >> 6, l = g & 63;
      union { int4 q4; u16 s[8]; } R;
#pragma unroll
      for (int j = 0; j < 8; ++j)                // natural k (A6 natural layout)
        R.s[j] = T[((l >> 4) * 8 + j) * 514 + nt * 16 + (l & 15)];
      *reinterpret_cast<int4*>(wfc + ((size_t)(q * 32 + nt) * 64 + l) * 8) = R.q4;
    }
    return;
  }
  int idx = (blk - 98) * 256 + t;                // small packs (< 64768)
  if (idx < 256) {                               // weff1 fp32 [8][32]
    int d = idx >> 5, o = idx & 31;
    wf1[idx] = weff_val(W1, d, o, 32);
    return;
  }
  if (idx < 9472) {                              // wp2: CT=2 KQ=1 (natural k)
    int local = idx - 256;
    int j = local & 7, l = (local >> 3) & 63, chunk = local >> 9;
    int ct = chunk & 1, tap = chunk >> 1;
    int k = (l >> 4) * 8 + j, n = ct * 16 + (l & 15);
    float v = tap < 8 ? weff_val(W2, tap, k * 32 + n, 1024) : rt2[k * 32 + n];
    wp2[local] = f2bf(v);
    return;
  }
  if (idx < 27904) {                             // wp3: CT=4 KQ=1 (perm'd k: H3 paired)
    int local = idx - 9472;
    int j = local & 7, l = (local >> 3) & 63, chunk = local >> 9;
    int ct = chunk & 3, tap = chunk >> 2;
    int k = kperm32((l >> 4) * 8 + j), n = ct * 16 + (l & 15);
    float v = tap < 8 ? weff_val(W3, tap, k * 64 + n, 2048) : rt3[k * 64 + n];
    wp3[local] = f2bf(v);
    return;
  }
  if (idx < 64768) {                             // wp4: CT=4 KQ=2 (perm'd k: H4 paired)
    int local = idx - 27904;
    int j = local & 7, l = (local >> 3) & 63, chunk = local >> 9;
    int q = chunk & 1, tmp = chunk >> 1;
    int ct = tmp & 3, tap = tmp >> 2;
    int k = q * 32 + kperm32((l >> 4) * 8 + j), n = ct * 16 + (l & 15);
    float v = tap < 8 ? weff_val(W4, tap, k * 64 + n, 4096) : rt4[k * 64 + n];
    wp4[local] = f2bf(v);
  }
}

// ---- mega conv kernel: block = 1 image (1024 thr, 16 waves), LDS-resident ---
// EXACT R8-benched structure (53.1 us). ONLY change: __launch_bounds__(1024, 2)
// -> per-wave register budget 256 (arch+acc) instead of the 128 (64+64 split)
// that (1024,4) pinned. LDS (125.7 KB) caps residency at 1 block/CU either
// way, so this is free headroom; removes the 64-arch-VGPR spill cliff
// (R5/R7/R11 lesson: VGPR_Count=64 + MB-scale FETCH/WRITE = scratch spill).
// Weight fragments loaded INSIDE their phase (R7 lesson: never hoist).
// LDS (bytes), temporally overlapped:
//   early : H1 [0,61568) 4 grp stride 962 int4 | XT [61568,65408) f32 30x32
//   mid   : H2 [75520,125696) [784][16] u32 (paired couts)
//   late  : H3 [0,16512) 4 grp stride 258 int4 | H4 [42496,75520) 8 grp stride 258
//           H5 [17408,42496) [196][64] u16 (natural)
__global__ __launch_bounds__(1024, 2) void conv_mega(
    const float* __restrict__ x,
    const float* __restrict__ wf1, const float* __restrict__ rt1, const float* __restrict__ b1,
    const u16* __restrict__ wp2, const float* __restrict__ b2,
    const u16* __restrict__ wp3, const float* __restrict__ b3,
    const u16* __restrict__ wp4, const float* __restrict__ b4,
    u16* __restrict__ A6) {
  extern __shared__ char smem[];
  int4* H1 = (int4*)smem;
  int4* H3 = (int4*)smem;
  u16*  H5 = (u16*)(smem + 17408);
  int4* H4 = (int4*)(smem + 42496);
  unsigned* H4u = (unsigned*)(smem + 42496);
  float* XT = (float*)(smem + 61568);
  int4*     H2 = (int4*)(smem + 75520);
  unsigned* H2u = (unsigned*)(smem + 75520);

  int img = blockIdx.x, tid = threadIdx.x;
  int lane = tid & 63, wid = tid >> 6;
  int kcb = lane >> 4, n0 = lane & 15;
  int4 z4 = make_int4(0, 0, 0, 0);
  f32x4 zz = {0.f, 0.f, 0.f, 0.f};

  // phase A: zero H1 (incl pads) + build padded XT
  for (int i = tid; i < 3848; i += 1024) H1[i] = z4;
  if (tid < 960) {
    int r = tid >> 5, c = tid & 31;
    bool in = (r >= 1) && (r <= 28) && (c >= 1) && (c <= 28);
    XT[tid] = in ? x[(size_t)img * 784 + (r - 1) * 28 + (c - 1)] : 0.f;
  }
  __syncthreads();

  // ---- conv1 (Cin=1, fp32) -> H1 bf16 chunks ----
  if (tid < 784) {
    int px = tid;
    int r = px / 28, c = px - 28 * (px / 28);
    float acc[32];
#pragma unroll
    for (int o = 0; o < 32; ++o) acc[o] = 0.f;
#pragma unroll
    for (int d = 0; d < 8; ++d) {
      float xv = XT[(r + 1 - DRS[d]) * 32 + (c + 1 - DCS[d])];
#pragma unroll
      for (int o = 0; o < 32; ++o) acc[o] = fmaf(xv, wf1[d * 32 + o], acc[o]);
    }
    float inv = 1.f / (float)((3 - (r == 0) - (r == 27)) * (3 - (c == 0) - (c == 27)) - 1);
    float xc = XT[(r + 1) * 32 + c + 1];
    unsigned pk[16];
#pragma unroll
    for (int h = 0; h < 16; ++h)
      pk[h] = pk2(eluf(acc[2 * h] * inv + xc * rt1[2 * h] + b1[2 * h]),
                  eluf(acc[2 * h + 1] * inv + xc * rt1[2 * h + 1] + b1[2 * h + 1]));
#pragma unroll
    for (int kc = 0; kc < 4; ++kc)
      H1[kc * 962 + (r + 1) * 32 + (c + 1)] =
          make_int4(pk[4 * kc], pk[4 * kc + 1], pk[4 * kc + 2], pk[4 * kc + 3]);
  }
  __syncthreads();

  // ---- conv2 (32->32, MFMA, NCT=2 shared-A): 16 waves x 49 tiles ----
  {
    bf16x8 w2[9][2];
#pragma unroll
    for (int tap = 0; tap < 9; ++tap)
#pragma unroll
      for (int ct = 0; ct < 2; ++ct)
        w2[tap][ct] = *(const bf16x8*)(wp2 + (tap * 2 + ct) * 512 + lane * 8);
    for (int t = wid; t < 49; t += 16) {
      int pxm = t * 16 + n0;
      int r = pxm / 28, c = pxm - 28 * (pxm / 28);
      f32x4 an[2] = {zz, zz}, ar[2] = {zz, zz};
#pragma unroll
      for (int d = 0; d < 8; ++d) {
        bf16x8 a = *(const bf16x8*)&H1[kcb * 962 + (r + 1 - DRS[d]) * 32 + (c + 1 - DCS[d])];
        an[0] = __builtin_amdgcn_mfma_f32_16x16x32_bf16(a, w2[d][0], an[0], 0, 0, 0);
        an[1] = __builtin_amdgcn_mfma_f32_16x16x32_bf16(a, w2[d][1], an[1], 0, 0, 0);
      }
      {
        bf16x8 a = *(const bf16x8*)&H1[kcb * 962 + (r + 1) * 32 + (c + 1)];
        ar[0] = __builtin_amdgcn_mfma_f32_16x16x32_bf16(a, w2[8][0], ar[0], 0, 0, 0);
        ar[1] = __builtin_amdgcn_mfma_f32_16x16x32_bf16(a, w2[8][1], ar[1], 0, 0, 0);
      }
#pragma unroll
      for (int j = 0; j < 4; ++j) {
        int pm = t * 16 + (lane >> 4) * 4 + j;
        int rm = pm / 28, cm = pm - 28 * (pm / 28);
        float inv = 1.f / (float)((3 - (rm == 0) - (rm == 27)) * (3 - (cm == 0) - (cm == 27)) - 1);
        H2u[pm * 16 + n0] = pk2(eluf(an[0][j] * inv + ar[0][j] + b2[n0]),
                                eluf(an[1][j] * inv + ar[1][j] + b2[16 + n0]));
      }
    }
  }
  __syncthreads();

  // ---- pool0: H2 -> H3 padded (pads = 0); zero H4 pads concurrently ----
  for (int i = tid; i < 1032; i += 1024) {
    int kc = i & 3, rem = i >> 2;
    int4 v = z4;
    if (rem < 256) {
      int pr = rem >> 4, pc = rem & 15;
      if (pr >= 1 && pr <= 14 && pc >= 1 && pc <= 14) {
        int px0 = (2 * (pr - 1)) * 28 + 2 * (pc - 1);
        union { int4 q; u16 s[8]; } A, B, C, D, R;
        A.q = H2[px0 * 4 + kc]; B.q = H2[(px0 + 1) * 4 + kc];
        C.q = H2[(px0 + 28) * 4 + kc]; D.q = H2[(px0 + 29) * 4 + kc];
#pragma unroll
        for (int e = 0; e < 8; ++e)
          R.s[e] = f2bf(fmaxf(fmaxf(bf2f(A.s[e]), bf2f(B.s[e])),
                              fmaxf(bf2f(C.s[e]), bf2f(D.s[e]))));
        v = R.q;
      }
    }
    H3[kc * 258 + rem] = v;
  }
  for (int i = tid; i < 2064; i += 1024) H4[i] = z4;
  __syncthreads();

  // ---- conv3 (32->64, MFMA, NCT=2 shared-A): 2 ct-groups x 8 strides ----
  {
    int ct0 = wid & 1, t0 = wid >> 1;
    bf16x8 w3[9][2];
#pragma unroll
    for (int tap = 0; tap < 9; ++tap)
#pragma unroll
      for (int cc = 0; cc < 2; ++cc)
        w3[tap][cc] = *(const bf16x8*)(wp3 + (tap * 4 + ct0 * 2 + cc) * 512 + lane * 8);
    for (int t = t0; t < 13; t += 8) {
      int pxm = t * 16 + n0; if (pxm > 195) pxm = 195;
      int r = pxm / 14, c = pxm - 14 * (pxm / 14);
      f32x4 an[2] = {zz, zz}, ar[2] = {zz, zz};
#pragma unroll
      for (int d = 0; d < 8; ++d) {
        bf16x8 a = *(const bf16x8*)&H3[kcb * 258 + (r + 1 - DRS[d]) * 16 + (c + 1 - DCS[d])];
        an[0] = __builtin_amdgcn_mfma_f32_16x16x32_bf16(a, w3[d][0], an[0], 0, 0, 0);
        an[1] = __builtin_amdgcn_mfma_f32_16x16x32_bf16(a, w3[d][1], an[1], 0, 0, 0);
      }
      {
        bf16x8 a = *(const bf16x8*)&H3[kcb * 258 + (r + 1) * 16 + (c + 1)];
        ar[0] = __builtin_amdgcn_mfma_f32_16x16x32_bf16(a, w3[8][0], ar[0], 0, 0, 0);
        ar[1] = __builtin_amdgcn_mfma_f32_16x16x32_bf16(a, w3[8][1], ar[1], 0, 0, 0);
      }
#pragma unroll
      for (int j = 0; j < 4; ++j) {
        int pm = t * 16 + (lane >> 4) * 4 + j;
        if (pm < 196) {
          int rm = pm / 14, cm = pm - 14 * (pm / 14);
          float inv = 1.f / (float)((3 - (rm == 0) - (rm == 13)) * (3 - (cm == 0) - (cm == 13)) - 1);
          unsigned v = pk2(eluf(an[0][j] * inv + ar[0][j] + b3[ct0 * 32 + n0]),
                           eluf(an[1][j] * inv + ar[1][j] + b3[ct0 * 32 + 16 + n0]));
          H4u[((ct0 * 4 + (n0 >> 2)) * 258 + (rm + 1) * 16 + (cm + 1)) * 4 + (n0 & 3)] = v;
        }
      }
    }
  }
  __syncthreads();

  // ---- conv4 (64->64, MFMA, NCT=1, weights resident once) ----
  {
    int ctg = wid & 3, t0 = wid >> 2;
    bf16x8 w4[9][2];
#pragma unroll
    for (int tap = 0; tap < 9; ++tap)
#pragma unroll
      for (int kq = 0; kq < 2; ++kq)
        w4[tap][kq] = *(const bf16x8*)(wp4 + ((tap * 4 + ctg) * 2 + kq) * 512 + lane * 8);
    for (int t = t0; t < 13; t += 4) {
      int pxm = t * 16 + n0; if (pxm > 195) pxm = 195;
      int r = pxm / 14, c = pxm - 14 * (pxm / 14);
      f32x4 an = zz, ar = zz;
#pragma unroll
      for (int d = 0; d < 8; ++d) {
        int rr = r + 1 - DRS[d], c2 = c + 1 - DCS[d];
#pragma unroll
        for (int kq = 0; kq < 2; ++kq) {
          bf16x8 a = *(const bf16x8*)&H4[(kq * 4 + kcb) * 258 + rr * 16 + c2];
          an = __builtin_amdgcn_mfma_f32_16x16x32_bf16(a, w4[d][kq], an, 0, 0, 0);
        }
      }
#pragma unroll
      for (int kq = 0; kq < 2; ++kq) {
        bf16x8 a = *(const bf16x8*)&H4[(kq * 4 + kcb) * 258 + (r + 1) * 16 + (c + 1)];
        ar = __builtin_amdgcn_mfma_f32_16x16x32_bf16(a, w4[8][kq], ar, 0, 0, 0);
      }
#pragma unroll
      for (int j = 0; j < 4; ++j) {
        int pm = t * 16 + (lane >> 4) * 4 + j;
        if (pm < 196) {
          int rm = pm / 14, cm = pm - 14 * (pm / 14);
          float inv = 1.f / (float)((3 - (rm == 0) - (rm == 13)) * (3 - (cm == 0) - (cm == 13)) - 1);
          int n = ctg * 16 + n0;
          H5[pm * 64 + n] = f2bf(eluf(an[j] * inv + ar[j] + b4[n]));
        }
      }
    }
  }
  __syncthreads();

  // ---- pool1: H5 [196][64] u16 natural -> global A6 [img][49*64] bf16 ----
  if (tid < 392) {
    int kc = tid & 7, q = tid >> 3;
    int r2 = q / 7, c2 = q - 7 * (q / 7);
    int px0 = (2 * r2) * 14 + 2 * c2;
    union { int4 q4; u16 s[8]; } A, B, C, D, R;
    A.q4 = *(const int4*)&H5[px0 * 64 + kc * 8];
    B.q4 = *(const int4*)&H5[(px0 + 1) * 64 + kc * 8];
    C.q4 = *(const int4*)&H5[(px0 + 14) * 64 + kc * 8];
    D.q4 = *(const int4*)&H5[(px0 + 15) * 64 + kc * 8];
#pragma unroll
    for (int e = 0; e < 8; ++e)
      R.s[e] = f2bf(fmaxf(fmaxf(bf2f(A.s[e]), bf2f(B.s[e])),
                          fmaxf(bf2f(C.s[e]), bf2f(D.s[e]))));
    *(int4*)(A6 + ((size_t)img * 49 + q) * 64 + kc * 8) = R.q4;
  }
}

// ---- FC1 bf16 MFMA, single-pass K=3136: 256 blocks (16 mt x 16 bn) x 2 waves
// epilogue fuses bias + ELU, writes bf16 h[256,512]
__global__ __launch_bounds__(128) void fc1_mfma(
    const u16* __restrict__ A6, const u16* __restrict__ wfc,
    const float* __restrict__ fc1b, u16* __restrict__ h) {
  int blk = blockIdx.x;
  int mt = blk & 15, bn = blk >> 4;
  int lane = threadIdx.x & 63, w = threadIdx.x >> 6;
  int NT = bn * 2 + w;                       // 16-col group 0..31
  f32x4 acc0 = {0.f, 0.f, 0.f, 0.f}, acc1 = {0.f, 0.f, 0.f, 0.f};
  const u16* Ab = A6 + (size_t)(mt * 16 + (lane & 15)) * 3136 + (lane >> 4) * 8;
  const u16* Bb = wfc + (size_t)NT * 512 + (size_t)lane * 8;
#pragma unroll 7
  for (int qq = 0; qq < 98; qq += 2) {       // two interleaved acc chains
    bf16x8 a0 = *(const bf16x8*)(Ab + qq * 32);
    bf16x8 b0 = *(const bf16x8*)(Bb + (size_t)qq * 16384);
    acc0 = __builtin_amdgcn_mfma_f32_16x16x32_bf16(a0, b0, acc0, 0, 0, 0);
    bf16x8 a1 = *(const bf16x8*)(Ab + qq * 32 + 32);
    bf16x8 b1 = *(const bf16x8*)(Bb + (size_t)qq * 16384 + 16384);
    acc1 = __builtin_amdgcn_mfma_f32_16x16x32_bf16(a1, b1, acc1, 0, 0, 0);
  }
#pragma unroll
  for (int j = 0; j < 4; ++j) {
    int row = mt * 16 + (lane >> 4) * 4 + j;
    int col = NT * 16 + (lane & 15);
    float v = acc0[j] + acc1[j] + fc1b[col];
    h[(size_t)row * 512 + col] = f2bf(eluf(v));
  }
}

// ---- FC2 (reads bf16 h) + bias + log_softmax -------------------------------
__global__ __launch_bounds__(64) void fc2_kernel(
    const u16* __restrict__ h, const float* __restrict__ W,
    const float* __restrict__ bias, float* __restrict__ out) {
  int bb = blockIdx.x;
  int t = threadIdx.x;
  float acc[10];
#pragma unroll
  for (int o = 0; o < 10; ++o) acc[o] = 0.f;
  bf16x8 hv = *(const bf16x8*)(h + (size_t)bb * 512 + t * 8);
#pragma unroll
  for (int kk = 0; kk < 8; ++kk) {
    float xv = bf2f((u16)hv[kk]);
    int k = t * 8 + kk;
#pragma unroll
    for (int o = 0; o < 10; ++o) acc[o] = fmaf(xv, W[k * 10 + o], acc[o]);
  }
#pragma unroll
  for (int o = 0; o < 10; ++o) {
    float v = acc[o];
#pragma unroll
    for (int s = 32; s >= 1; s >>= 1) v += __shfl_xor(v, s);
    acc[o] = v + bias[o];
  }
  float m = acc[0];
#pragma unroll
  for (int o = 1; o < 10; ++o) m = fmaxf(m, acc[o]);
  float sum = 0.f;
#pragma unroll
  for (int o = 0; o < 10; ++o) sum += __expf(acc[o] - m);
  float lse = m + __logf(sum);
  if (t < 10) out[bb * 10 + t] = acc[t] - lse;
}

extern "C" void kernel_launch(void* const* d_in, const int* in_sizes, int n_in,
                              void* d_out, int out_size, void* d_ws, size_t ws_size,
                              hipStream_t stream) {
  const float* x    = (const float*)d_in[0];
  const float* W1   = (const float*)d_in[7];
  const float* r1   = (const float*)d_in[8];
  const float* b1   = (const float*)d_in[9];
  const float* W2   = (const float*)d_in[10];
  const float* r2   = (const float*)d_in[11];
  const float* b2   = (const float*)d_in[12];
  const float* W3   = (const float*)d_in[13];
  const float* r3   = (const float*)d_in[14];
  const float* b3   = (const float*)d_in[15];
  const float* W4   = (const float*)d_in[16];
  const float* r4   = (const float*)d_in[17];
  const float* b4   = (const float*)d_in[18];
  const float* fc1W = (const float*)d_in[19];
  const float* fc1b = (const float*)d_in[20];
  const float* fc2W = (const float*)d_in[21];
  const float* fc2b = (const float*)d_in[22];

  char* wsb = (char*)d_ws;
  float* wf1  = (float*)(wsb + 0);        // 1024 B
  u16*   wp2  = (u16*)(wsb + 1024);       // 18432 B
  u16*   wp3  = (u16*)(wsb + 19456);      // 36864 B
  u16*   wp4  = (u16*)(wsb + 56320);      // 73728 B
  u16*   wfc  = (u16*)(wsb + 130048);     // 3211264 B
  u16*   A6   = (u16*)(wsb + 3341312);    // 1605632 B  [256][3136] bf16
  u16*   hbuf = (u16*)(wsb + 4946944);    // 262144 B   [256][512] bf16

  pack_all<<<351, 256, 0, stream>>>(W1, W2, r2, W3, r3, W4, r4, fc1W,
                                    wf1, wp2, wp3, wp4, wfc);

  (void)hipFuncSetAttribute((const void*)conv_mega,
                            hipFuncAttributeMaxDynamicSharedMemorySize, 125696);
  conv_mega<<<256, 1024, 125696, stream>>>(x, wf1, r1, b1, wp2, b2, wp3, b3,
                                           wp4, b4, A6);

  fc1_mfma<<<256, 128, 0, stream>>>(A6, wfc, fc1b, hbuf);
  fc2_kernel<<<256, 64, 0, stream>>>(hbuf, fc2W, fc2b, (float*)d_out);
}